// Round 1
// baseline (494.894 us; speedup 1.0000x reference)
//
#include <hip/hip_runtime.h>

#define HW 4096
#define CC 128

__device__ __forceinline__ float dot4(float4 a, float4 b) {
    return (a.x*b.x + a.y*b.y) + (a.z*b.z + a.w*b.w);
}

// ---------- Kernel 1: Q and K 1x1 convs -> position-major [b][p][16] ----------
// grid 128: bid<64 -> Q from x_forward (Wq,bq); else K from x (Wk,bk)
__global__ __launch_bounds__(256) void qk_kernel(
    const float* __restrict__ xf, const float* __restrict__ xx,
    const float* __restrict__ Wq, const float* __restrict__ bq,
    const float* __restrict__ Wk, const float* __restrict__ bk,
    float* __restrict__ Qt, float* __restrict__ Kt)
{
    __shared__ __align__(16) float sW[16*128];
    __shared__ float sB[16];
    int bid = blockIdx.x;
    bool isQ = bid < 64;
    const float* src  = isQ ? xf : xx;
    const float* W    = isQ ? Wq : Wk;
    const float* bias = isQ ? bq : bk;
    float* dst        = isQ ? Qt : Kt;
    int tid = threadIdx.x;
    for (int e = tid; e < 2048; e += 256) sW[e] = W[e];
    if (tid < 16) sB[tid] = bias[tid];
    __syncthreads();

    int pg = (bid & 63) * 256 + tid;          // 0..16383
    int b = pg >> 12, p = pg & 4095;
    const float* sp = src + (size_t)b * CC * HW + p;

    float acc[16];
    #pragma unroll
    for (int o = 0; o < 16; o++) acc[o] = sB[o];

    for (int c4 = 0; c4 < 128; c4 += 4) {
        float x0 = sp[(c4+0)*HW];
        float x1 = sp[(c4+1)*HW];
        float x2 = sp[(c4+2)*HW];
        float x3 = sp[(c4+3)*HW];
        #pragma unroll
        for (int o = 0; o < 16; o++) {
            float4 w = *(const float4*)&sW[o*128 + c4];
            acc[o] += w.x*x0 + w.y*x1 + w.z*x2 + w.w*x3;
        }
    }
    float4* outp = (float4*)(dst + (size_t)pg * 16);
    outp[0] = make_float4(acc[0],acc[1],acc[2],acc[3]);
    outp[1] = make_float4(acc[4],acc[5],acc[6],acc[7]);
    outp[2] = make_float4(acc[8],acc[9],acc[10],acc[11]);
    outp[3] = make_float4(acc[12],acc[13],acc[14],acc[15]);
}

// ---------- Kernel 2: V = Wv * x_backward + bv, layout [b][c][p] ----------
// grid 256 = b(4) x og(4) x pt(16); block 256 = oz(2) x pz(128)
__global__ __launch_bounds__(256) void v_kernel(
    const float* __restrict__ xb, const float* __restrict__ Wv,
    const float* __restrict__ bv, float* __restrict__ V)
{
    __shared__ __align__(16) float sW[32*128];
    int bid = blockIdx.x;
    int b = bid >> 6, og = (bid >> 4) & 3, pt = bid & 15;
    int tid = threadIdx.x;
    for (int e = tid; e < 4096; e += 256) sW[e] = Wv[og*4096 + e];
    __syncthreads();

    int oz = tid >> 7, pz = tid & 127;
    int p0 = pt*256 + pz, p1 = p0 + 128;
    const float* sp = xb + (size_t)b * CC * HW;

    float acc0[16], acc1[16];
    #pragma unroll
    for (int j = 0; j < 16; j++) { acc0[j] = 0.f; acc1[j] = 0.f; }

    for (int c4 = 0; c4 < 128; c4 += 4) {
        float a0 = sp[(c4+0)*HW + p0], a1 = sp[(c4+1)*HW + p0];
        float a2 = sp[(c4+2)*HW + p0], a3 = sp[(c4+3)*HW + p0];
        float b0 = sp[(c4+0)*HW + p1], b1 = sp[(c4+1)*HW + p1];
        float b2 = sp[(c4+2)*HW + p1], b3 = sp[(c4+3)*HW + p1];
        #pragma unroll
        for (int j = 0; j < 16; j++) {
            float4 w = *(const float4*)&sW[(oz*16 + j)*128 + c4];
            acc0[j] += w.x*a0 + w.y*a1 + w.z*a2 + w.w*a3;
            acc1[j] += w.x*b0 + w.y*b1 + w.z*b2 + w.w*b3;
        }
    }
    #pragma unroll
    for (int j = 0; j < 16; j++) {
        int o = og*32 + oz*16 + j;
        float bb = bv[o];
        V[(((size_t)b*CC + o)<<12) + p0] = acc0[j] + bb;
        V[(((size_t)b*CC + o)<<12) + p1] = acc1[j] + bb;
    }
}

// ---------- Kernel 3: fused max/argmax over q of K[k].Q[q] ----------
// grid 256 = b(4) x kt(64); block 256: qc = tid>>5 (8 q-chunks), kk = tid&31 (2 k each)
__global__ __launch_bounds__(256) void att_kernel(
    const float* __restrict__ Qt, const float* __restrict__ Kt,
    float* __restrict__ maxv, int* __restrict__ idxv)
{
    __shared__ float sM[8][64];
    __shared__ int   sI[8][64];
    int bid = blockIdx.x;
    int b = bid >> 6, kt = bid & 63;
    int tid = threadIdx.x;
    int qc = tid >> 5, kk = tid & 31;
    int kbase = kt*64;
    int lk0 = kk*2, lk1 = lk0 + 1;

    const float4* K0 = (const float4*)(Kt + ((size_t)(b*HW + kbase + lk0))*16);
    const float4* K1 = (const float4*)(Kt + ((size_t)(b*HW + kbase + lk1))*16);
    float4 k0a = K0[0], k0b = K0[1], k0c = K0[2], k0d = K0[3];
    float4 k1a = K1[0], k1b = K1[1], k1c = K1[2], k1d = K1[3];

    float m0 = -1e30f, m1 = -1e30f;
    int i0 = 0, i1 = 0;
    const float4* Qp = (const float4*)(Qt + (size_t)b*HW*16);

    int q = qc * 512;
    for (int it = 0; it < 512; it++, q++) {
        float4 qa = Qp[q*4+0], qb = Qp[q*4+1], qcv = Qp[q*4+2], qd = Qp[q*4+3];
        float d0 = (dot4(k0a,qa) + dot4(k0b,qb)) + (dot4(k0c,qcv) + dot4(k0d,qd));
        float d1 = (dot4(k1a,qa) + dot4(k1b,qb)) + (dot4(k1c,qcv) + dot4(k1d,qd));
        if (d0 > m0) { m0 = d0; i0 = q; }   // ascending q + strict '>' = first occurrence
        if (d1 > m1) { m1 = d1; i1 = q; }
    }
    sM[qc][lk0] = m0; sM[qc][lk1] = m1;
    sI[qc][lk0] = i0; sI[qc][lk1] = i1;
    __syncthreads();
    if (tid < 64) {
        float m = sM[0][tid]; int i = sI[0][tid];
        #pragma unroll
        for (int c = 1; c < 8; c++) {     // ascending chunks: strict '>' keeps lowest idx
            float mm = sM[c][tid];
            if (mm > m) { m = mm; i = sI[c][tid]; }
        }
        maxv[b*HW + kbase + tid] = m;
        idxv[b*HW + kbase + tid] = i;
    }
}

// ---------- Kernel 4: gather selected_value[b][c][p] = V[b][c][idx[b][p]] ----------
// grid 1024 = b(4) x ct(4) x pt(64); block 256 = cz(4) x pl(64)
__global__ __launch_bounds__(256) void gather_kernel(
    const float* __restrict__ V, const int* __restrict__ idxv,
    float* __restrict__ sel)
{
    int bid = blockIdx.x;
    int b = bid >> 8, ct = (bid >> 6) & 3, pt = bid & 63;
    int tid = threadIdx.x;
    int cz = tid >> 6, pl = tid & 63;
    int p = pt*64 + pl;
    int ip = idxv[b*HW + p];
    const float* vb = V  + ((size_t)b*CC << 12);
    float*       sb = sel + ((size_t)b*CC << 12);
    #pragma unroll
    for (int cc = 0; cc < 8; cc++) {
        int c = ct*32 + cz*8 + cc;
        sb[(c<<12) + p] = vb[(c<<12) + ip];
    }
}

// ---------- Kernel 5: 3x3 conv over [x ; sel] (256 ch) + bias, * maxv, + x ----------
// grid 512 = b(4) x ty(4) x tx(4) x og(8); block 256 = oz(4) x pi(64)
// block tile: 16 out-ch x 16x16 spatial; thread: 4 out-ch x 2x2 positions
__global__ __launch_bounds__(256) void conv_kernel(
    const float* __restrict__ x, const float* __restrict__ sel,
    const float* __restrict__ Wf, const float* __restrict__ bf,
    const float* __restrict__ maxv, float* __restrict__ out)
{
    __shared__ __align__(16) float sIn[16*324];   // 16 ci x 18x18 halo tile
    __shared__ __align__(16) float sW[144*16];    // [ci*9+tap][16 o]

    int bid = blockIdx.x;
    int og = bid & 7, tx = (bid >> 3) & 3, ty = (bid >> 5) & 3, b = bid >> 7;
    int tid = threadIdx.x;
    int oz = tid >> 6, pi = tid & 63;
    int y0 = (pi >> 3) * 2, x0 = (pi & 7) * 2;
    int obase = og * 16;

    float acc[4][4];
    #pragma unroll
    for (int j = 0; j < 4; j++)
        #pragma unroll
        for (int t = 0; t < 4; t++) acc[j][t] = 0.f;

    const float* xbase = x   + ((size_t)b*CC << 12);
    const float* sbase = sel + ((size_t)b*CC << 12);

    for (int cb = 0; cb < 16; cb++) {
        __syncthreads();
        // stage input halo tile (zero-padded)
        for (int e = tid; e < 5184; e += 256) {
            int ci  = e / 324;
            int rem = e - ci*324;
            int iy  = rem / 18;
            int ix  = rem - iy*18;
            int gy = ty*16 - 1 + iy;
            int gx = tx*16 - 1 + ix;
            int gc = cb*16 + ci;
            float v = 0.f;
            if ((unsigned)gy < 64u && (unsigned)gx < 64u) {
                int off = (gy << 6) + gx;
                v = (gc < 128) ? xbase[(gc << 12) + off]
                               : sbase[((gc - 128) << 12) + off];
            }
            sIn[e] = v;
        }
        // stage weights transposed: sW[(ci*9+tap)*16 + o]
        #pragma unroll
        for (int it = 0; it < 9; it++) {
            int e = it*256 + tid;                 // 0..2303
            int o_l = e & 15, r = e >> 4;         // r = ci*9+tap in 0..143
            sW[e] = Wf[(size_t)(obase + o_l)*2304 + cb*144 + r];
        }
        __syncthreads();

        #pragma unroll 4
        for (int ci = 0; ci < 16; ci++) {
            float iv[4][4];
            #pragma unroll
            for (int yy = 0; yy < 4; yy++) {
                const float* rowp = &sIn[ci*324 + (y0 + yy)*18 + x0];
                float2 aa = *(const float2*)rowp;
                float2 bb = *(const float2*)(rowp + 2);
                iv[yy][0] = aa.x; iv[yy][1] = aa.y; iv[yy][2] = bb.x; iv[yy][3] = bb.y;
            }
            #pragma unroll
            for (int t = 0; t < 9; t++) {
                const int dy = t / 3, dx = t % 3;
                float4 w = *(const float4*)&sW[(ci*9 + t)*16 + oz*4];
                #pragma unroll
                for (int r = 0; r < 2; r++)
                    #pragma unroll
                    for (int s = 0; s < 2; s++) {
                        float ivv = iv[r + dy][s + dx];
                        acc[0][r*2+s] = fmaf(w.x, ivv, acc[0][r*2+s]);
                        acc[1][r*2+s] = fmaf(w.y, ivv, acc[1][r*2+s]);
                        acc[2][r*2+s] = fmaf(w.z, ivv, acc[2][r*2+s]);
                        acc[3][r*2+s] = fmaf(w.w, ivv, acc[3][r*2+s]);
                    }
            }
        }
    }

    // epilogue: out = x + maxv * (conv + bf)
    #pragma unroll
    for (int r = 0; r < 2; r++)
        #pragma unroll
        for (int s = 0; s < 2; s++) {
            int oy = ty*16 + y0 + r, ox = tx*16 + x0 + s;
            int p = (oy << 6) + ox;
            float mv = maxv[(b << 12) + p];
            #pragma unroll
            for (int j = 0; j < 4; j++) {
                int o = obase + oz*4 + j;
                out[(((size_t)b*CC + o) << 12) + p] =
                    xbase[(o << 12) + p] + mv * (acc[j][r*2+s] + bf[o]);
            }
        }
}

extern "C" void kernel_launch(void* const* d_in, const int* in_sizes, int n_in,
                              void* d_out, int out_size, void* d_ws, size_t ws_size,
                              hipStream_t stream) {
    (void)in_sizes; (void)n_in; (void)out_size; (void)ws_size;
    const float* x  = (const float*)d_in[0];
    const float* xf = (const float*)d_in[1];
    const float* xb = (const float*)d_in[2];
    const float* Wq = (const float*)d_in[3];
    const float* bq = (const float*)d_in[4];
    const float* Wk = (const float*)d_in[5];
    const float* bk = (const float*)d_in[6];
    const float* Wv = (const float*)d_in[7];
    const float* bv = (const float*)d_in[8];
    const float* Wf = (const float*)d_in[9];
    const float* bf = (const float*)d_in[10];
    float* out = (float*)d_out;

    float* ws   = (float*)d_ws;
    float* Qt   = ws;                 // 4*4096*16 = 262144
    float* Kt   = Qt + 262144;        // 262144
    float* V    = Kt + 262144;        // 4*128*4096 = 2097152
    float* sel  = V  + 2097152;       // 2097152
    float* mx   = sel + 2097152;      // 16384
    int*   idxv = (int*)(mx + 16384); // 16384 ints

    hipLaunchKernelGGL(qk_kernel,     dim3(128),  dim3(256), 0, stream, xf, x, Wq, bq, Wk, bk, Qt, Kt);
    hipLaunchKernelGGL(v_kernel,      dim3(256),  dim3(256), 0, stream, xb, Wv, bv, V);
    hipLaunchKernelGGL(att_kernel,    dim3(256),  dim3(256), 0, stream, Qt, Kt, mx, idxv);
    hipLaunchKernelGGL(gather_kernel, dim3(1024), dim3(256), 0, stream, V, idxv, sel);
    hipLaunchKernelGGL(conv_kernel,   dim3(512),  dim3(256), 0, stream, x, sel, Wf, bf, mx, out);
}

// Round 2
// 290.986 us; speedup vs baseline: 1.7007x; 1.7007x over previous
//
#include <hip/hip_runtime.h>

#define HW 4096
#define CC 128

typedef unsigned short ushort_t;
typedef unsigned int uint_t;
typedef __attribute__((ext_vector_type(8))) short short8;
typedef __attribute__((ext_vector_type(4))) float f32x4;

__device__ __forceinline__ float dot4(float4 a, float4 b) {
    return (a.x*b.x + a.y*b.y) + (a.z*b.z + a.w*b.w);
}

__device__ __forceinline__ ushort_t f2bf(float f) {
    union { float f; uint_t u; } cv; cv.f = f;
    uint_t r = cv.u + 0x7fffu + ((cv.u >> 16) & 1u);
    return (ushort_t)(r >> 16);
}

__device__ __forceinline__ void gl2lds16(const ushort_t* g, ushort_t* l) {
    __builtin_amdgcn_global_load_lds(
        (const __attribute__((address_space(1))) unsigned int*)g,
        (__attribute__((address_space(3))) unsigned int*)l, 16, 0, 0);
}

// ---------- Kernel 1: Q and K 1x1 convs -> position-major [b][p][16] ----------
__global__ __launch_bounds__(256) void qk_kernel(
    const float* __restrict__ xf, const float* __restrict__ xx,
    const float* __restrict__ Wq, const float* __restrict__ bq,
    const float* __restrict__ Wk, const float* __restrict__ bk,
    float* __restrict__ Qt, float* __restrict__ Kt)
{
    __shared__ __align__(16) float sW[16*128];
    __shared__ float sB[16];
    int bid = blockIdx.x;
    bool isQ = bid < 64;
    const float* src  = isQ ? xf : xx;
    const float* W    = isQ ? Wq : Wk;
    const float* bias = isQ ? bq : bk;
    float* dst        = isQ ? Qt : Kt;
    int tid = threadIdx.x;
    for (int e = tid; e < 2048; e += 256) sW[e] = W[e];
    if (tid < 16) sB[tid] = bias[tid];
    __syncthreads();

    int pg = (bid & 63) * 256 + tid;
    int b = pg >> 12, p = pg & 4095;
    const float* sp = src + (size_t)b * CC * HW + p;

    float acc[16];
    #pragma unroll
    for (int o = 0; o < 16; o++) acc[o] = sB[o];

    for (int c4 = 0; c4 < 128; c4 += 4) {
        float x0 = sp[(c4+0)*HW];
        float x1 = sp[(c4+1)*HW];
        float x2 = sp[(c4+2)*HW];
        float x3 = sp[(c4+3)*HW];
        #pragma unroll
        for (int o = 0; o < 16; o++) {
            float4 w = *(const float4*)&sW[o*128 + c4];
            acc[o] += w.x*x0 + w.y*x1 + w.z*x2 + w.w*x3;
        }
    }
    float4* outp = (float4*)(dst + (size_t)pg * 16);
    outp[0] = make_float4(acc[0],acc[1],acc[2],acc[3]);
    outp[1] = make_float4(acc[4],acc[5],acc[6],acc[7]);
    outp[2] = make_float4(acc[8],acc[9],acc[10],acc[11]);
    outp[3] = make_float4(acc[12],acc[13],acc[14],acc[15]);
}

// ---------- Kernel 2: V = Wv * x_backward + bv, layout [b][c][p] ----------
__global__ __launch_bounds__(256) void v_kernel(
    const float* __restrict__ xb, const float* __restrict__ Wv,
    const float* __restrict__ bv, float* __restrict__ V)
{
    __shared__ __align__(16) float sW[32*128];
    int bid = blockIdx.x;
    int b = bid >> 6, og = (bid >> 4) & 3, pt = bid & 15;
    int tid = threadIdx.x;
    for (int e = tid; e < 4096; e += 256) sW[e] = Wv[og*4096 + e];
    __syncthreads();

    int oz = tid >> 7, pz = tid & 127;
    int p0 = pt*256 + pz, p1 = p0 + 128;
    const float* sp = xb + (size_t)b * CC * HW;

    float acc0[16], acc1[16];
    #pragma unroll
    for (int j = 0; j < 16; j++) { acc0[j] = 0.f; acc1[j] = 0.f; }

    for (int c4 = 0; c4 < 128; c4 += 4) {
        float a0 = sp[(c4+0)*HW + p0], a1 = sp[(c4+1)*HW + p0];
        float a2 = sp[(c4+2)*HW + p0], a3 = sp[(c4+3)*HW + p0];
        float b0 = sp[(c4+0)*HW + p1], b1 = sp[(c4+1)*HW + p1];
        float b2 = sp[(c4+2)*HW + p1], b3 = sp[(c4+3)*HW + p1];
        #pragma unroll
        for (int j = 0; j < 16; j++) {
            float4 w = *(const float4*)&sW[(oz*16 + j)*128 + c4];
            acc0[j] += w.x*a0 + w.y*a1 + w.z*a2 + w.w*a3;
            acc1[j] += w.x*b0 + w.y*b1 + w.z*b2 + w.w*b3;
        }
    }
    #pragma unroll
    for (int j = 0; j < 16; j++) {
        int o = og*32 + oz*16 + j;
        float bb = bv[o];
        V[(((size_t)b*CC + o)<<12) + p0] = acc0[j] + bb;
        V[(((size_t)b*CC + o)<<12) + p1] = acc1[j] + bb;
    }
}

// ---------- Kernel 3: fused max/argmax over q of K[k].Q[q] ----------
__global__ __launch_bounds__(256) void att_kernel(
    const float* __restrict__ Qt, const float* __restrict__ Kt,
    float* __restrict__ maxv, int* __restrict__ idxv)
{
    __shared__ float sM[8][64];
    __shared__ int   sI[8][64];
    int bid = blockIdx.x;
    int b = bid >> 6, kt = bid & 63;
    int tid = threadIdx.x;
    int qc = tid >> 5, kk = tid & 31;
    int kbase = kt*64;
    int lk0 = kk*2, lk1 = lk0 + 1;

    const float4* K0 = (const float4*)(Kt + ((size_t)(b*HW + kbase + lk0))*16);
    const float4* K1 = (const float4*)(Kt + ((size_t)(b*HW + kbase + lk1))*16);
    float4 k0a = K0[0], k0b = K0[1], k0c = K0[2], k0d = K0[3];
    float4 k1a = K1[0], k1b = K1[1], k1c = K1[2], k1d = K1[3];

    float m0 = -1e30f, m1 = -1e30f;
    int i0 = 0, i1 = 0;
    const float4* Qp = (const float4*)(Qt + (size_t)b*HW*16);

    int q = qc * 512;
    for (int it = 0; it < 512; it++, q++) {
        float4 qa = Qp[q*4+0], qb = Qp[q*4+1], qcv = Qp[q*4+2], qd = Qp[q*4+3];
        float d0 = (dot4(k0a,qa) + dot4(k0b,qb)) + (dot4(k0c,qcv) + dot4(k0d,qd));
        float d1 = (dot4(k1a,qa) + dot4(k1b,qb)) + (dot4(k1c,qcv) + dot4(k1d,qd));
        if (d0 > m0) { m0 = d0; i0 = q; }
        if (d1 > m1) { m1 = d1; i1 = q; }
    }
    sM[qc][lk0] = m0; sM[qc][lk1] = m1;
    sI[qc][lk0] = i0; sI[qc][lk1] = i1;
    __syncthreads();
    if (tid < 64) {
        float m = sM[0][tid]; int i = sI[0][tid];
        #pragma unroll
        for (int c = 1; c < 8; c++) {
            float mm = sM[c][tid];
            if (mm > m) { m = mm; i = sI[c][tid]; }
        }
        maxv[b*HW + tid + kbase] = m;
        idxv[b*HW + tid + kbase] = i;
    }
}

// ---------- Kernel 4: zero the 66x66 border of xsel_t ----------
// 4 b x 260 border sites x 256 c; one uint4 (8 ushort) per thread slot
__global__ __launch_bounds__(256) void border_kernel(ushort_t* __restrict__ xsel)
{
    int g = blockIdx.x * 256 + threadIdx.x;       // 0..33279
    if (g >= 33280) return;
    int b = g / 8320;
    int rem = g - b * 8320;
    int si = rem >> 5;                            // border site 0..259
    int ch = rem & 31;                            // 8-ushort chunk
    int y, x;
    if (si < 66)      { y = 0;  x = si; }
    else if (si < 132){ y = 65; x = si - 66; }
    else { int t = si - 132; y = 1 + (t >> 1); x = (t & 1) ? 65 : 0; }
    int site = y * 66 + x;
    uint4* dst = (uint4*)(xsel + ((size_t)(b*4356 + site))*256);
    dst[ch] = make_uint4(0,0,0,0);
}

// ---------- Kernel 5: x f32 [c][y][x] -> xsel_t[b][y+1][x+1][c] bf16 (c<128) ----------
// grid 256 = b(4) x y(64)
__global__ __launch_bounds__(256) void xt_kernel(
    const float* __restrict__ x, ushort_t* __restrict__ xsel)
{
    __shared__ ushort_t sT[64*130];
    int bid = blockIdx.x;
    int b = bid >> 6, y = bid & 63;
    int tid = threadIdx.x;
    int cq = tid >> 6, xx = tid & 63;
    const float* src = x + ((size_t)b << 19) + (y << 6) + xx;
    #pragma unroll 4
    for (int k = 0; k < 32; k++) {
        int c = cq*32 + k;
        sT[xx*130 + c] = f2bf(src[(size_t)c << 12]);
    }
    __syncthreads();
    uint_t* dst = (uint_t*)(xsel + ((size_t)(b*4356 + (y+1)*66 + 1))*256);
    #pragma unroll
    for (int k = 0; k < 16; k++) {
        int idx = k*256 + tid;        // 0..4095
        int s = idx >> 6, u = idx & 63;
        uint_t v = *(const uint_t*)&sT[s*130 + u*2];
        dst[s*128 + u] = v;
    }
}

// ---------- Kernel 6: Wf f32 -> Wt bf16 [og][cb][tap][o32][ci32] ----------
__global__ __launch_bounds__(256) void wt_kernel(
    const float* __restrict__ Wf, ushort_t* __restrict__ Wt)
{
    int t = blockIdx.x * 256 + threadIdx.x;       // 0..36863
    if (t >= 36864) return;
    int cg = t & 3;
    int o = (t >> 2) & 31;
    int tc = t >> 7;                              // (og*8+cb)*9+tap
    int tap = tc % 9;
    int rest = tc / 9;
    int cb = rest & 7, og = rest >> 3;
    union { ushort_t s[8]; uint4 v; } pk;
    #pragma unroll
    for (int j = 0; j < 8; j++) {
        int ci = cg*8 + j;
        pk.s[j] = f2bf(Wf[(size_t)(og*32 + o)*2304 + (cb*32 + ci)*9 + tap]);
    }
    *(uint4*)(Wt + (size_t)t*8) = pk.v;
}

// ---------- Kernel 7: gather V columns -> xsel_t[...][128+c] bf16 ----------
// grid 256 = b(4) x pt(64); thread: (pp=tid>>2, cq=tid&3) -> 32 channels
__global__ __launch_bounds__(256) void gather_kernel(
    const float* __restrict__ V, const int* __restrict__ idxv,
    ushort_t* __restrict__ xsel)
{
    int bid = blockIdx.x;
    int b = bid >> 6, pt = bid & 63;
    int tid = threadIdx.x;
    int pp = tid >> 2, cq = tid & 3;
    int p = pt*64 + pp;
    int ip = idxv[(b << 12) + p];
    const float* vb = V + ((size_t)b << 19) + ip;
    int site = ((p >> 6) + 1)*66 + (p & 63) + 1;
    ushort_t* dst = xsel + ((size_t)(b*4356 + site))*256 + 128 + cq*32;
    #pragma unroll
    for (int k = 0; k < 4; k++) {
        union { ushort_t s[8]; uint4 v; } pk;
        #pragma unroll
        for (int j = 0; j < 8; j++) {
            int c = cq*32 + k*8 + j;
            pk.s[j] = f2bf(vb[(size_t)c << 12]);
        }
        *(uint4*)(dst + k*8) = pk.v;
    }
}

// ---------- Kernel 8: 3x3 conv as bf16 MFMA shift-GEMM ----------
// grid 256 = b(4) x ty(4) x tx(4) x og(4); block 256 = 4 waves
// block: 16x16 spatial x 32 outch; wave: 4 rows x 32 outch
__global__ __launch_bounds__(256) void conv_kernel(
    const float* __restrict__ x, const ushort_t* __restrict__ xsel,
    const ushort_t* __restrict__ Wt, const float* __restrict__ bf,
    const float* __restrict__ maxv, float* __restrict__ out)
{
    __shared__ __align__(16) ushort_t sIn[336*32];   // 21504 B (324 sites used)
    __shared__ __align__(16) ushort_t sW[9*32*32];   // 18432 B

    int bid = blockIdx.x;
    int og = bid & 3, tx = (bid >> 2) & 3, ty = (bid >> 4) & 3, b = bid >> 6;
    int tid = threadIdx.x;
    int wave = tid >> 6, lane = tid & 63;
    int l15 = lane & 15, quad = lane >> 4;

    const ushort_t* xsel_base = xsel + ((size_t)(b*4356 + (ty*16)*66 + tx*16))*256;
    const ushort_t* wt_base   = Wt + (size_t)og*8*9216;

    f32x4 acc[4][2];
    #pragma unroll
    for (int mi = 0; mi < 4; mi++)
        #pragma unroll
        for (int ni = 0; ni < 2; ni++) acc[mi][ni] = (f32x4)0.f;

    int l4q = lane >> 2, l4 = lane & 3;

    for (int cb = 0; cb < 8; cb++) {
        if (cb) __syncthreads();
        // stage input tile: 21 regions x 1024 B (16 sites each)
        for (int r = wave; r < 21; r += 4) {
            int site = r*16 + l4q;                 // 0..335
            int iy = site / 18, ix = site - iy*18;
            const ushort_t* g = xsel_base + (size_t)(iy*66 + ix)*256 + cb*32 + l4*8;
            gl2lds16(g, &sIn[r*512]);
        }
        // stage weights: 18 regions x 1024 B
        for (int r = wave; r < 18; r += 4) {
            const ushort_t* g = wt_base + (size_t)cb*9216 + r*512 + lane*8;
            gl2lds16(g, &sW[r*512]);
        }
        __syncthreads();

        #pragma unroll
        for (int tap = 0; tap < 9; tap++) {
            const int dy = tap / 3, dx = tap % 3;
            short8 B0 = *(const short8*)&sW[(tap*32 +      l15)*32 + quad*8];
            short8 B1 = *(const short8*)&sW[(tap*32 + 16 + l15)*32 + quad*8];
            #pragma unroll
            for (int mi = 0; mi < 4; mi++) {
                int row = wave*4 + mi + dy;        // 0..17
                short8 A = *(const short8*)&sIn[(row*18 + l15 + dx)*32 + quad*8];
                acc[mi][0] = __builtin_amdgcn_mfma_f32_16x16x32_bf16(A, B0, acc[mi][0], 0, 0, 0);
                acc[mi][1] = __builtin_amdgcn_mfma_f32_16x16x32_bf16(A, B1, acc[mi][1], 0, 0, 0);
            }
        }
    }

    // epilogue: out = x + maxv * (conv + bf)
    int y0 = ty*16, x0 = tx*16;
    const float* xb_ = x   + ((size_t)b << 19);
    float*       ob  = out + ((size_t)b << 19);
    const float* mxb = maxv + (b << 12);
    #pragma unroll
    for (int mi = 0; mi < 4; mi++) {
        int y = y0 + wave*4 + mi;
        int p = (y << 6) + x0 + quad*4;
        float4 mv = *(const float4*)&mxb[p];
        #pragma unroll
        for (int ni = 0; ni < 2; ni++) {
            int o = og*32 + ni*16 + l15;
            float bfo = bf[o];
            float4 xv = *(const float4*)&xb_[((size_t)o << 12) + p];
            float4 r;
            r.x = xv.x + mv.x * (acc[mi][ni][0] + bfo);
            r.y = xv.y + mv.y * (acc[mi][ni][1] + bfo);
            r.z = xv.z + mv.z * (acc[mi][ni][2] + bfo);
            r.w = xv.w + mv.w * (acc[mi][ni][3] + bfo);
            *(float4*)&ob[((size_t)o << 12) + p] = r;
        }
    }
}

extern "C" void kernel_launch(void* const* d_in, const int* in_sizes, int n_in,
                              void* d_out, int out_size, void* d_ws, size_t ws_size,
                              hipStream_t stream) {
    (void)in_sizes; (void)n_in; (void)out_size; (void)ws_size;
    const float* x  = (const float*)d_in[0];
    const float* xf = (const float*)d_in[1];
    const float* xb = (const float*)d_in[2];
    const float* Wq = (const float*)d_in[3];
    const float* bq = (const float*)d_in[4];
    const float* Wk = (const float*)d_in[5];
    const float* bk = (const float*)d_in[6];
    const float* Wv = (const float*)d_in[7];
    const float* bv = (const float*)d_in[8];
    const float* Wf = (const float*)d_in[9];
    const float* bf = (const float*)d_in[10];
    float* out = (float*)d_out;

    float* ws   = (float*)d_ws;
    float* Qt   = ws;                         // 262144 f
    float* Kt   = Qt + 262144;                // 262144 f
    float* V    = Kt + 262144;                // 2097152 f
    float* mx   = V  + 2097152;               // 16384 f
    int*   idxv = (int*)(mx + 16384);         // 16384 i
    ushort_t* xsel = (ushort_t*)(idxv + 16384);   // 4*4356*256 = 4460544 ush (+16K slack)
    ushort_t* Wt   = xsel + 4460544 + 16384;      // 294912 ush

    hipLaunchKernelGGL(qk_kernel,     dim3(128), dim3(256), 0, stream, xf, x, Wq, bq, Wk, bk, Qt, Kt);
    hipLaunchKernelGGL(v_kernel,      dim3(256), dim3(256), 0, stream, xb, Wv, bv, V);
    hipLaunchKernelGGL(att_kernel,    dim3(256), dim3(256), 0, stream, Qt, Kt, mx, idxv);
    hipLaunchKernelGGL(border_kernel, dim3(130), dim3(256), 0, stream, xsel);
    hipLaunchKernelGGL(xt_kernel,     dim3(256), dim3(256), 0, stream, x, xsel);
    hipLaunchKernelGGL(wt_kernel,     dim3(144), dim3(256), 0, stream, Wf, Wt);
    hipLaunchKernelGGL(gather_kernel, dim3(256), dim3(256), 0, stream, V, idxv, xsel);
    hipLaunchKernelGGL(conv_kernel,   dim3(256), dim3(256), 0, stream, x, xsel, Wt, bf, mx, out);
}

// Round 3
// 234.574 us; speedup vs baseline: 2.1098x; 1.2405x over previous
//
#include <hip/hip_runtime.h>

#define HW 4096
#define CC 128

typedef unsigned short ushort_t;
typedef unsigned int uint_t;
typedef __attribute__((ext_vector_type(8))) short short8;
typedef __attribute__((ext_vector_type(4))) float f32x4;

__device__ __forceinline__ float dot4(float4 a, float4 b) {
    return (a.x*b.x + a.y*b.y) + (a.z*b.z + a.w*b.w);
}

__device__ __forceinline__ ushort_t f2bf(float f) {
    union { float f; uint_t u; } cv; cv.f = f;
    uint_t r = cv.u + 0x7fffu + ((cv.u >> 16) & 1u);
    return (ushort_t)(r >> 16);
}

__device__ __forceinline__ void gl2lds16(const ushort_t* g, ushort_t* l) {
    __builtin_amdgcn_global_load_lds(
        (const __attribute__((address_space(1))) unsigned int*)g,
        (__attribute__((address_space(3))) unsigned int*)l, 16, 0, 0);
}

__device__ __forceinline__ void gl2lds16f(const float* g, float* l) {
    __builtin_amdgcn_global_load_lds(
        (const __attribute__((address_space(1))) unsigned int*)g,
        (__attribute__((address_space(3))) unsigned int*)l, 16, 0, 0);
}

// ---------- Kernel 1: Q and K 1x1 convs -> position-major [b][p][16] ----------
__global__ __launch_bounds__(256) void qk_kernel(
    const float* __restrict__ xf, const float* __restrict__ xx,
    const float* __restrict__ Wq, const float* __restrict__ bq,
    const float* __restrict__ Wk, const float* __restrict__ bk,
    float* __restrict__ Qt, float* __restrict__ Kt)
{
    __shared__ __align__(16) float sW[16*128];
    __shared__ float sB[16];
    int bid = blockIdx.x;
    bool isQ = bid < 64;
    const float* src  = isQ ? xf : xx;
    const float* W    = isQ ? Wq : Wk;
    const float* bias = isQ ? bq : bk;
    float* dst        = isQ ? Qt : Kt;
    int tid = threadIdx.x;
    for (int e = tid; e < 2048; e += 256) sW[e] = W[e];
    if (tid < 16) sB[tid] = bias[tid];
    __syncthreads();

    int pg = (bid & 63) * 256 + tid;
    int b = pg >> 12, p = pg & 4095;
    const float* sp = src + (size_t)b * CC * HW + p;

    float acc[16];
    #pragma unroll
    for (int o = 0; o < 16; o++) acc[o] = sB[o];

    for (int c4 = 0; c4 < 128; c4 += 4) {
        float x0 = sp[(c4+0)*HW];
        float x1 = sp[(c4+1)*HW];
        float x2 = sp[(c4+2)*HW];
        float x3 = sp[(c4+3)*HW];
        #pragma unroll
        for (int o = 0; o < 16; o++) {
            float4 w = *(const float4*)&sW[o*128 + c4];
            acc[o] += w.x*x0 + w.y*x1 + w.z*x2 + w.w*x3;
        }
    }
    float4* outp = (float4*)(dst + (size_t)pg * 16);
    outp[0] = make_float4(acc[0],acc[1],acc[2],acc[3]);
    outp[1] = make_float4(acc[4],acc[5],acc[6],acc[7]);
    outp[2] = make_float4(acc[8],acc[9],acc[10],acc[11]);
    outp[3] = make_float4(acc[12],acc[13],acc[14],acc[15]);
}

// ---------- Kernel 2: V = Wv * x_backward + bv, layout [b][c][p] ----------
__global__ __launch_bounds__(256) void v_kernel(
    const float* __restrict__ xb, const float* __restrict__ Wv,
    const float* __restrict__ bv, float* __restrict__ V)
{
    __shared__ __align__(16) float sW[32*128];
    int bid = blockIdx.x;
    int b = bid >> 6, og = (bid >> 4) & 3, pt = bid & 15;
    int tid = threadIdx.x;
    for (int e = tid; e < 4096; e += 256) sW[e] = Wv[og*4096 + e];
    __syncthreads();

    int oz = tid >> 7, pz = tid & 127;
    int p0 = pt*256 + pz, p1 = p0 + 128;
    const float* sp = xb + (size_t)b * CC * HW;

    float acc0[16], acc1[16];
    #pragma unroll
    for (int j = 0; j < 16; j++) { acc0[j] = 0.f; acc1[j] = 0.f; }

    for (int c4 = 0; c4 < 128; c4 += 4) {
        float a0 = sp[(c4+0)*HW + p0], a1 = sp[(c4+1)*HW + p0];
        float a2 = sp[(c4+2)*HW + p0], a3 = sp[(c4+3)*HW + p0];
        float b0 = sp[(c4+0)*HW + p1], b1 = sp[(c4+1)*HW + p1];
        float b2 = sp[(c4+2)*HW + p1], b3 = sp[(c4+3)*HW + p1];
        #pragma unroll
        for (int j = 0; j < 16; j++) {
            float4 w = *(const float4*)&sW[(oz*16 + j)*128 + c4];
            acc0[j] += w.x*a0 + w.y*a1 + w.z*a2 + w.w*a3;
            acc1[j] += w.x*b0 + w.y*b1 + w.z*b2 + w.w*b3;
        }
    }
    #pragma unroll
    for (int j = 0; j < 16; j++) {
        int o = og*32 + oz*16 + j;
        float bb = bv[o];
        V[(((size_t)b*CC + o)<<12) + p0] = acc0[j] + bb;
        V[(((size_t)b*CC + o)<<12) + p1] = acc1[j] + bb;
    }
}

// ---------- Kernel 3: fused max/argmax over q of K[k].Q[q] ----------
// grid 512 = b(4) x kt(128); block 512 = 8 waves; block covers 32 k's.
// Lane holds 2 K-vectors; 32 q-streams (wave*4+lanegroup); Q double-buffered in LDS.
#define QCHUNK 256
__global__ __launch_bounds__(512) void att_kernel(
    const float* __restrict__ Qt, const float* __restrict__ Kt,
    float* __restrict__ maxv, int* __restrict__ idxv)
{
    __shared__ __align__(16) float sQ[2][QCHUNK*16];   // 2 x 16 KiB
    __shared__ float sM[32][33];
    __shared__ int   sI[32][33];

    int bid = blockIdx.x;
    int b = bid >> 7, kt = bid & 127;
    int tid = threadIdx.x;
    int wave = tid >> 6, lane = tid & 63;
    int kk = lane & 15;            // k-pair index within block
    int lg = lane >> 4;            // 0..3
    int stream = wave*4 + lg;      // 0..31

    // load this lane's two K vectors (held in registers)
    const float4* K0 = (const float4*)(Kt + ((size_t)(b*HW) + kt*32 + kk*2)*16);
    float4 k0a=K0[0], k0b=K0[1], k0c=K0[2], k0d=K0[3];
    float4 k1a=K0[4], k1b=K0[5], k1c=K0[6], k1d=K0[7];

    const float* qsrc = Qt + ((size_t)b*HW)*16;

    // stage chunk 0
    {
        const float* g = qsrc;
        gl2lds16f(g + (wave    )*256 + lane*4, &sQ[0][(wave    )*256]);
        gl2lds16f(g + (wave + 8)*256 + lane*4, &sQ[0][(wave + 8)*256]);
    }

    float m0 = -1e30f, m1 = -1e30f;
    int i0 = 0, i1 = 0;

    for (int c = 0; c < 16; c++) {
        __syncthreads();                        // drains chunk-c loads
        if (c < 15) {                           // prefetch next chunk
            const float* g = qsrc + (c+1)*(QCHUNK*16);
            int nb = (c+1) & 1;
            gl2lds16f(g + (wave    )*256 + lane*4, &sQ[nb][(wave    )*256]);
            gl2lds16f(g + (wave + 8)*256 + lane*4, &sQ[nb][(wave + 8)*256]);
        }
        const float* buf = sQ[c & 1];
        #pragma unroll
        for (int it = 0; it < 8; it++) {
            int ql = it*32 + stream;
            const float4* Qp = (const float4*)&buf[ql*16];
            float4 qa = Qp[0], qb = Qp[1], qcv = Qp[2], qd = Qp[3];
            float d0 = (dot4(k0a,qa) + dot4(k0b,qb)) + (dot4(k0c,qcv) + dot4(k0d,qd));
            float d1 = (dot4(k1a,qa) + dot4(k1b,qb)) + (dot4(k1c,qcv) + dot4(k1d,qd));
            int q = c*QCHUNK + ql;
            if (d0 > m0) { m0 = d0; i0 = q; }   // q ascending within stream
            if (d1 > m1) { m1 = d1; i1 = q; }
        }
    }

    sM[kk*2    ][stream] = m0;  sI[kk*2    ][stream] = i0;
    sM[kk*2 + 1][stream] = m1;  sI[kk*2 + 1][stream] = i1;
    __syncthreads();
    if (tid < 32) {
        float m = sM[tid][0]; int i = sI[tid][0];
        #pragma unroll 8
        for (int s = 1; s < 32; s++) {
            float mm = sM[tid][s]; int ii = sI[tid][s];
            if (mm > m || (mm == m && ii < i)) { m = mm; i = ii; }  // first-occurrence
        }
        maxv[(b << 12) + kt*32 + tid] = m;
        idxv[(b << 12) + kt*32 + tid] = i;
    }
}

// ---------- Kernel 4: zero the 66x66 border of xsel_t ----------
__global__ __launch_bounds__(256) void border_kernel(ushort_t* __restrict__ xsel)
{
    int g = blockIdx.x * 256 + threadIdx.x;       // 0..33279
    if (g >= 33280) return;
    int b = g / 8320;
    int rem = g - b * 8320;
    int si = rem >> 5;
    int ch = rem & 31;
    int y, x;
    if (si < 66)      { y = 0;  x = si; }
    else if (si < 132){ y = 65; x = si - 66; }
    else { int t = si - 132; y = 1 + (t >> 1); x = (t & 1) ? 65 : 0; }
    int site = y * 66 + x;
    uint4* dst = (uint4*)(xsel + ((size_t)(b*4356 + site))*256);
    dst[ch] = make_uint4(0,0,0,0);
}

// ---------- Kernel 5: x f32 [c][y][x] -> xsel_t[b][y+1][x+1][c] bf16 (c<128) ----------
__global__ __launch_bounds__(256) void xt_kernel(
    const float* __restrict__ x, ushort_t* __restrict__ xsel)
{
    __shared__ ushort_t sT[64*130];
    int bid = blockIdx.x;
    int b = bid >> 6, y = bid & 63;
    int tid = threadIdx.x;
    int cq = tid >> 6, xx = tid & 63;
    const float* src = x + ((size_t)b << 19) + (y << 6) + xx;
    #pragma unroll 4
    for (int k = 0; k < 32; k++) {
        int c = cq*32 + k;
        sT[xx*130 + c] = f2bf(src[(size_t)c << 12]);
    }
    __syncthreads();
    uint_t* dst = (uint_t*)(xsel + ((size_t)(b*4356 + (y+1)*66 + 1))*256);
    #pragma unroll
    for (int k = 0; k < 16; k++) {
        int idx = k*256 + tid;
        int s = idx >> 6, u = idx & 63;
        uint_t v = *(const uint_t*)&sT[s*130 + u*2];
        dst[s*128 + u] = v;
    }
}

// ---------- Kernel 6: Wf f32 -> Wt bf16 [og][cb][tap][o32][ci32] ----------
__global__ __launch_bounds__(256) void wt_kernel(
    const float* __restrict__ Wf, ushort_t* __restrict__ Wt)
{
    int t = blockIdx.x * 256 + threadIdx.x;
    if (t >= 36864) return;
    int cg = t & 3;
    int o = (t >> 2) & 31;
    int tc = t >> 7;
    int tap = tc % 9;
    int rest = tc / 9;
    int cb = rest & 7, og = rest >> 3;
    union { ushort_t s[8]; uint4 v; } pk;
    #pragma unroll
    for (int j = 0; j < 8; j++) {
        int ci = cg*8 + j;
        pk.s[j] = f2bf(Wf[(size_t)(og*32 + o)*2304 + (cb*32 + ci)*9 + tap]);
    }
    *(uint4*)(Wt + (size_t)t*8) = pk.v;
}

// ---------- Kernel 7: gather V columns -> xsel_t[...][128+c] bf16 ----------
__global__ __launch_bounds__(256) void gather_kernel(
    const float* __restrict__ V, const int* __restrict__ idxv,
    ushort_t* __restrict__ xsel)
{
    int bid = blockIdx.x;
    int b = bid >> 6, pt = bid & 63;
    int tid = threadIdx.x;
    int pp = tid >> 2, cq = tid & 3;
    int p = pt*64 + pp;
    int ip = idxv[(b << 12) + p];
    const float* vb = V + ((size_t)b << 19) + ip;
    int site = ((p >> 6) + 1)*66 + (p & 63) + 1;
    ushort_t* dst = xsel + ((size_t)(b*4356 + site))*256 + 128 + cq*32;
    #pragma unroll
    for (int k = 0; k < 4; k++) {
        union { ushort_t s[8]; uint4 v; } pk;
        #pragma unroll
        for (int j = 0; j < 8; j++) {
            int c = cq*32 + k*8 + j;
            pk.s[j] = f2bf(vb[(size_t)c << 12]);
        }
        *(uint4*)(dst + k*8) = pk.v;
    }
}

// ---------- Kernel 8: 3x3 conv as bf16 MFMA shift-GEMM ----------
__global__ __launch_bounds__(256) void conv_kernel(
    const float* __restrict__ x, const ushort_t* __restrict__ xsel,
    const ushort_t* __restrict__ Wt, const float* __restrict__ bf,
    const float* __restrict__ maxv, float* __restrict__ out)
{
    __shared__ __align__(16) ushort_t sIn[336*32];
    __shared__ __align__(16) ushort_t sW[9*32*32];

    int bid = blockIdx.x;
    int og = bid & 3, tx = (bid >> 2) & 3, ty = (bid >> 4) & 3, b = bid >> 6;
    int tid = threadIdx.x;
    int wave = tid >> 6, lane = tid & 63;
    int l15 = lane & 15, quad = lane >> 4;

    const ushort_t* xsel_base = xsel + ((size_t)(b*4356 + (ty*16)*66 + tx*16))*256;
    const ushort_t* wt_base   = Wt + (size_t)og*8*9216;

    f32x4 acc[4][2];
    #pragma unroll
    for (int mi = 0; mi < 4; mi++)
        #pragma unroll
        for (int ni = 0; ni < 2; ni++) acc[mi][ni] = (f32x4)0.f;

    int l4q = lane >> 2, l4 = lane & 3;

    for (int cb = 0; cb < 8; cb++) {
        if (cb) __syncthreads();
        for (int r = wave; r < 21; r += 4) {
            int site = r*16 + l4q;
            int iy = site / 18, ix = site - iy*18;
            const ushort_t* g = xsel_base + (size_t)(iy*66 + ix)*256 + cb*32 + l4*8;
            gl2lds16(g, &sIn[r*512]);
        }
        for (int r = wave; r < 18; r += 4) {
            const ushort_t* g = wt_base + (size_t)cb*9216 + r*512 + lane*8;
            gl2lds16(g, &sW[r*512]);
        }
        __syncthreads();

        #pragma unroll
        for (int tap = 0; tap < 9; tap++) {
            const int dy = tap / 3, dx = tap % 3;
            short8 B0 = *(const short8*)&sW[(tap*32 +      l15)*32 + quad*8];
            short8 B1 = *(const short8*)&sW[(tap*32 + 16 + l15)*32 + quad*8];
            #pragma unroll
            for (int mi = 0; mi < 4; mi++) {
                int row = wave*4 + mi + dy;
                short8 A = *(const short8*)&sIn[(row*18 + l15 + dx)*32 + quad*8];
                acc[mi][0] = __builtin_amdgcn_mfma_f32_16x16x32_bf16(A, B0, acc[mi][0], 0, 0, 0);
                acc[mi][1] = __builtin_amdgcn_mfma_f32_16x16x32_bf16(A, B1, acc[mi][1], 0, 0, 0);
            }
        }
    }

    int y0 = ty*16, x0 = tx*16;
    const float* xb_ = x   + ((size_t)b << 19);
    float*       ob  = out + ((size_t)b << 19);
    const float* mxb = maxv + (b << 12);
    #pragma unroll
    for (int mi = 0; mi < 4; mi++) {
        int y = y0 + wave*4 + mi;
        int p = (y << 6) + x0 + quad*4;
        float4 mv = *(const float4*)&mxb[p];
        #pragma unroll
        for (int ni = 0; ni < 2; ni++) {
            int o = og*32 + ni*16 + l15;
            float bfo = bf[o];
            float4 xv = *(const float4*)&xb_[((size_t)o << 12) + p];
            float4 r;
            r.x = xv.x + mv.x * (acc[mi][ni][0] + bfo);
            r.y = xv.y + mv.y * (acc[mi][ni][1] + bfo);
            r.z = xv.z + mv.z * (acc[mi][ni][2] + bfo);
            r.w = xv.w + mv.w * (acc[mi][ni][3] + bfo);
            *(float4*)&ob[((size_t)o << 12) + p] = r;
        }
    }
}

extern "C" void kernel_launch(void* const* d_in, const int* in_sizes, int n_in,
                              void* d_out, int out_size, void* d_ws, size_t ws_size,
                              hipStream_t stream) {
    (void)in_sizes; (void)n_in; (void)out_size; (void)ws_size;
    const float* x  = (const float*)d_in[0];
    const float* xf = (const float*)d_in[1];
    const float* xb = (const float*)d_in[2];
    const float* Wq = (const float*)d_in[3];
    const float* bq = (const float*)d_in[4];
    const float* Wk = (const float*)d_in[5];
    const float* bk = (const float*)d_in[6];
    const float* Wv = (const float*)d_in[7];
    const float* bv = (const float*)d_in[8];
    const float* Wf = (const float*)d_in[9];
    const float* bf = (const float*)d_in[10];
    float* out = (float*)d_out;

    float* ws   = (float*)d_ws;
    float* Qt   = ws;                         // 262144 f
    float* Kt   = Qt + 262144;                // 262144 f
    float* V    = Kt + 262144;                // 2097152 f
    float* mx   = V  + 2097152;               // 16384 f
    int*   idxv = (int*)(mx + 16384);         // 16384 i
    ushort_t* xsel = (ushort_t*)(idxv + 16384);   // 4*4356*256 ush
    ushort_t* Wt   = xsel + 4460544 + 16384;      // 294912 ush

    hipLaunchKernelGGL(qk_kernel,     dim3(128), dim3(256), 0, stream, xf, x, Wq, bq, Wk, bk, Qt, Kt);
    hipLaunchKernelGGL(v_kernel,      dim3(256), dim3(256), 0, stream, xb, Wv, bv, V);
    hipLaunchKernelGGL(att_kernel,    dim3(512), dim3(512), 0, stream, Qt, Kt, mx, idxv);
    hipLaunchKernelGGL(border_kernel, dim3(130), dim3(256), 0, stream, xsel);
    hipLaunchKernelGGL(xt_kernel,     dim3(256), dim3(256), 0, stream, x, xsel);
    hipLaunchKernelGGL(wt_kernel,     dim3(144), dim3(256), 0, stream, Wf, Wt);
    hipLaunchKernelGGL(gather_kernel, dim3(256), dim3(256), 0, stream, V, idxv, xsel);
    hipLaunchKernelGGL(conv_kernel,   dim3(256), dim3(256), 0, stream, x, xsel, Wt, bf, mx, out);
}